// Round 1
// baseline (1489.006 us; speedup 1.0000x reference)
//
#include <hip/hip_runtime.h>
#include <math.h>

#define U_NUM 100000
#define I_NUM 50000
#define NE    2000000
#define EMB   64
#define NLAYERS 3

static inline int ceil_div(int a, int b){ return (a + b - 1) / b; }

// ---------------- CSR construction ----------------

__global__ void count_k(const int* __restrict__ u_idx, const int* __restrict__ i_idx,
                        int* __restrict__ cnt_u, int* __restrict__ cnt_i, int n){
  int e = blockIdx.x * blockDim.x + threadIdx.x;
  if (e < n){
    atomicAdd(&cnt_u[u_idx[e]], 1);
    atomicAdd(&cnt_i[i_idx[e]], 1);
  }
}

// 256 threads x 8 elems = 2048 per block; exclusive scan within chunk.
__global__ void scan1_k(const int* __restrict__ in, int* __restrict__ out,
                        int* __restrict__ partials, int n){
  __shared__ int sdata[256];
  int tid = threadIdx.x;
  int base = blockIdx.x * 2048 + tid * 8;
  int v[8]; int s = 0;
#pragma unroll
  for (int k = 0; k < 8; ++k){ int i = base + k; int x = (i < n) ? in[i] : 0; v[k] = s; s += x; }
  sdata[tid] = s; __syncthreads();
  for (int off = 1; off < 256; off <<= 1){
    int t = (tid >= off) ? sdata[tid - off] : 0;
    __syncthreads();
    sdata[tid] += t;
    __syncthreads();
  }
  int toff = (tid > 0) ? sdata[tid - 1] : 0;
  if (tid == 255) partials[blockIdx.x] = sdata[255];
#pragma unroll
  for (int k = 0; k < 8; ++k){ int i = base + k; if (i < n) out[i] = v[k] + toff; }
}

__global__ void scan2_k(int* partials, int nb){
  if (blockIdx.x == 0 && threadIdx.x == 0){
    int s = 0;
    for (int i = 0; i < nb; ++i){ int x = partials[i]; partials[i] = s; s += x; }
  }
}

// add block offsets; also init cursors = offsets and write the final sentinel.
__global__ void scan3_k(int* __restrict__ out, const int* __restrict__ partials,
                        int* __restrict__ cur, int n, int total){
  int tid = threadIdx.x;
  int base = blockIdx.x * 2048 + tid * 8;
  int add = partials[blockIdx.x];
#pragma unroll
  for (int k = 0; k < 8; ++k){
    int i = base + k;
    if (i < n){ int val = out[i] + add; out[i] = val; cur[i] = val; }
  }
  if (blockIdx.x == 0 && tid == 0) out[n] = total;
}

__global__ void fill_k(const int* __restrict__ u_idx, const int* __restrict__ i_idx,
                       int* __restrict__ cur_u, int* __restrict__ cur_i,
                       int* __restrict__ adj_u, int* __restrict__ adj_i, int n){
  int e = blockIdx.x * blockDim.x + threadIdx.x;
  if (e < n){
    int u = u_idx[e], it = i_idx[e];
    adj_u[atomicAdd(&cur_u[u], 1)] = it;   // user-major CSR: neighbors are items
    adj_i[atomicAdd(&cur_i[it], 1)] = u;   // item-major CSR: neighbors are users
  }
}

__global__ void norms_k(const int* __restrict__ cnt, float* __restrict__ inv,
                        float* __restrict__ invs, int n){
  int r = blockIdx.x * blockDim.x + threadIdx.x;
  if (r < n){
    int c = cnt[r];
    float d = (c > 0) ? (float)c : 1.0f;
    inv[r]  = 1.0f / d;
    invs[r] = 1.0f / sqrtf(d);
  }
}

__global__ void init_out_k(const float* __restrict__ ue, const float* __restrict__ ie,
                           float* __restrict__ out){
  int idx = blockIdx.x * blockDim.x + threadIdx.x;
  const int un = U_NUM * EMB;
  const int tot = un + I_NUM * EMB;
  if (idx < un) out[idx] = ue[idx];
  else if (idx < tot) out[idx] = ie[idx - un];
}

__global__ void scale_k(float* __restrict__ out, int n, float s){
  int i = blockIdx.x * blockDim.x + threadIdx.x;
  if (i < n) out[i] *= s;
}

// ---------------- gather SpMM ----------------
// out[r] = post[r] * sum_{n in N(r)} (HAS_PRE ? pre[n] : 1) * src[n]
// 16 lanes per row, float4 per lane (256B/row, coalesced). Unroll x4 for ILP.

#define ACC4(vv, ww) { acc.x += (ww)*(vv).x; acc.y += (ww)*(vv).y; \
                       acc.z += (ww)*(vv).z; acc.w += (ww)*(vv).w; }

template<bool HAS_PRE, bool HAS_SUM>
__global__ void spmm_k(const int* __restrict__ offs, const int* __restrict__ adj,
                       const float* __restrict__ src, const float* __restrict__ pre,
                       const float* __restrict__ post, float* __restrict__ dst,
                       float* __restrict__ sum, int nrows){
  int t = blockIdx.x * blockDim.x + threadIdx.x;
  int row = t >> 4;
  if (row >= nrows) return;
  int lane = t & 15;
  int beg = offs[row], end = offs[row + 1];
  float4 acc = make_float4(0.f, 0.f, 0.f, 0.f);
  int j = beg;
  for (; j + 3 < end; j += 4){
    int n0 = adj[j], n1 = adj[j+1], n2 = adj[j+2], n3 = adj[j+3];
    float4 v0 = ((const float4*)(src + (size_t)n0 * EMB))[lane];
    float4 v1 = ((const float4*)(src + (size_t)n1 * EMB))[lane];
    float4 v2 = ((const float4*)(src + (size_t)n2 * EMB))[lane];
    float4 v3 = ((const float4*)(src + (size_t)n3 * EMB))[lane];
    float w0 = HAS_PRE ? pre[n0] : 1.0f;
    float w1 = HAS_PRE ? pre[n1] : 1.0f;
    float w2 = HAS_PRE ? pre[n2] : 1.0f;
    float w3 = HAS_PRE ? pre[n3] : 1.0f;
    ACC4(v0, w0); ACC4(v1, w1); ACC4(v2, w2); ACC4(v3, w3);
  }
  for (; j < end; ++j){
    int n0 = adj[j];
    float4 v0 = ((const float4*)(src + (size_t)n0 * EMB))[lane];
    float w0 = HAS_PRE ? pre[n0] : 1.0f;
    ACC4(v0, w0);
  }
  float p = post[row];
  acc.x *= p; acc.y *= p; acc.z *= p; acc.w *= p;
  ((float4*)(dst + (size_t)row * EMB))[lane] = acc;
  if (HAS_SUM){
    float4* sp = ((float4*)(sum + (size_t)row * EMB)) + lane;
    float4 s = *sp;
    s.x += acc.x; s.y += acc.y; s.z += acc.z; s.w += acc.w;
    *sp = s;
  }
}

// ---------------- driver ----------------

extern "C" void kernel_launch(void* const* d_in, const int* in_sizes, int n_in,
                              void* d_out, int out_size, void* d_ws, size_t ws_size,
                              hipStream_t stream){
  const float* user_emb = (const float*)d_in[0];
  const float* item_emb = (const float*)d_in[1];
  const int*   u_idx    = (const int*)d_in[2];
  const int*   i_idx    = (const int*)d_in[3];
  float* out = (float*)d_out;

  char* w = (char*)d_ws;
  size_t off = 0;
  auto alloc = [&](size_t bytes) -> void* {
    void* p = (void*)(w + off);
    off += (bytes + 255) & ~(size_t)255;
    return p;
  };
  int* cnt_u  = (int*)alloc((size_t)U_NUM * 4);
  int* cnt_i  = (int*)alloc((size_t)I_NUM * 4);
  int* offs_u = (int*)alloc((size_t)(U_NUM + 1) * 4);
  int* offs_i = (int*)alloc((size_t)(I_NUM + 1) * 4);
  int* cur_u  = (int*)alloc((size_t)U_NUM * 4);
  int* cur_i  = (int*)alloc((size_t)I_NUM * 4);
  int* part_u = (int*)alloc(64 * 4);
  int* part_i = (int*)alloc(64 * 4);
  int* adj_u  = (int*)alloc((size_t)NE * 4);
  int* adj_i  = (int*)alloc((size_t)NE * 4);
  float* du_inv  = (float*)alloc((size_t)U_NUM * 4);
  float* du_invs = (float*)alloc((size_t)U_NUM * 4);
  float* di_inv  = (float*)alloc((size_t)I_NUM * 4);
  float* di_invs = (float*)alloc((size_t)I_NUM * 4);
  float* user_e = (float*)alloc((size_t)U_NUM * EMB * 4);
  float* item_e = (float*)alloc((size_t)I_NUM * EMB * 4);
  float* tmp_i  = (float*)alloc((size_t)I_NUM * EMB * 4);
  float* tmp_u  = (float*)alloc((size_t)U_NUM * EMB * 4);

  hipMemsetAsync(cnt_u, 0, (size_t)U_NUM * 4, stream);
  hipMemsetAsync(cnt_i, 0, (size_t)I_NUM * 4, stream);

  count_k<<<ceil_div(NE, 256), 256, 0, stream>>>(u_idx, i_idx, cnt_u, cnt_i, NE);

  int nbu = ceil_div(U_NUM, 2048), nbi = ceil_div(I_NUM, 2048);
  scan1_k<<<nbu, 256, 0, stream>>>(cnt_u, offs_u, part_u, U_NUM);
  scan1_k<<<nbi, 256, 0, stream>>>(cnt_i, offs_i, part_i, I_NUM);
  scan2_k<<<1, 64, 0, stream>>>(part_u, nbu);
  scan2_k<<<1, 64, 0, stream>>>(part_i, nbi);
  scan3_k<<<nbu, 256, 0, stream>>>(offs_u, part_u, cur_u, U_NUM, NE);
  scan3_k<<<nbi, 256, 0, stream>>>(offs_i, part_i, cur_i, I_NUM, NE);

  fill_k<<<ceil_div(NE, 256), 256, 0, stream>>>(u_idx, i_idx, cur_u, cur_i, adj_u, adj_i, NE);

  norms_k<<<ceil_div(U_NUM, 256), 256, 0, stream>>>(cnt_u, du_inv, du_invs, U_NUM);
  norms_k<<<ceil_div(I_NUM, 256), 256, 0, stream>>>(cnt_i, di_inv, di_invs, I_NUM);

  init_out_k<<<ceil_div((U_NUM + I_NUM) * EMB, 256), 256, 0, stream>>>(user_emb, item_emb, out);

  float* sum_u = out;
  float* sum_i = out + (size_t)U_NUM * EMB;
  const float* ue_src = user_emb;
  const float* ie_src = item_emb;
  for (int l = 0; l < NLAYERS; ++l){
    // A: tmp_i = d_i_inv * R^T (d_u_inv_sqrt * user_e)
    spmm_k<true, false><<<ceil_div(I_NUM * 16, 256), 256, 0, stream>>>(
        offs_i, adj_i, ue_src, du_invs, di_inv, tmp_i, nullptr, I_NUM);
    // B: user_e = d_u_inv_sqrt * R tmp_i ; sum_u += user_e
    spmm_k<false, true><<<ceil_div(U_NUM * 16, 256), 256, 0, stream>>>(
        offs_u, adj_u, tmp_i, nullptr, du_invs, user_e, sum_u, U_NUM);
    // C: tmp_u = d_u_inv * R (d_i_inv_sqrt * item_e)
    spmm_k<true, false><<<ceil_div(U_NUM * 16, 256), 256, 0, stream>>>(
        offs_u, adj_u, ie_src, di_invs, du_inv, tmp_u, nullptr, U_NUM);
    // D: item_e = d_i_inv_sqrt * R^T tmp_u ; sum_i += item_e
    spmm_k<false, true><<<ceil_div(I_NUM * 16, 256), 256, 0, stream>>>(
        offs_i, adj_i, tmp_u, nullptr, di_invs, item_e, sum_i, I_NUM);
    ue_src = user_e; ie_src = item_e;
  }

  scale_k<<<ceil_div((U_NUM + I_NUM) * EMB, 256), 256, 0, stream>>>(
      out, (U_NUM + I_NUM) * EMB, 1.0f / (NLAYERS + 1));
}

// Round 2
// 1084.028 us; speedup vs baseline: 1.3736x; 1.3736x over previous
//
#include <hip/hip_runtime.h>
#include <math.h>

#define U_NUM 100000
#define I_NUM 50000
#define NE    2000000
#define EMB   64
#define NLAYERS 3

// bucketing: 256 rows per bucket
#define BSH   8
#define NBU_U ((U_NUM + 255) >> 8)   // 391
#define NBU_I ((I_NUM + 255) >> 8)   // 196
#define CHUNK 8192
#define NBLK_E ((NE + CHUNK - 1) / CHUNK)

static inline int ceil_div(int a, int b){ return (a + b - 1) / b; }

// ---------------- phase 1: bucket partition ----------------

__global__ void bucket_hist_k(const int* __restrict__ u_idx, const int* __restrict__ i_idx,
                              int* __restrict__ bcnt_u, int* __restrict__ bcnt_i){
  __shared__ int hU[NBU_U];
  __shared__ int hI[NBU_I];
  for (int t = threadIdx.x; t < NBU_U; t += 256) hU[t] = 0;
  for (int t = threadIdx.x; t < NBU_I; t += 256) hI[t] = 0;
  __syncthreads();
  int base = blockIdx.x * CHUNK;
  int end = min(base + CHUNK, NE);
  for (int e = base + threadIdx.x; e < end; e += 256){
    atomicAdd(&hU[u_idx[e] >> BSH], 1);
    atomicAdd(&hI[i_idx[e] >> BSH], 1);
  }
  __syncthreads();
  for (int t = threadIdx.x; t < NBU_U; t += 256) if (hU[t]) atomicAdd(&bcnt_u[t], hU[t]);
  for (int t = threadIdx.x; t < NBU_I; t += 256) if (hI[t]) atomicAdd(&bcnt_i[t], hI[t]);
}

// single-block exclusive scan, n <= 512; writes offs[0..n] (sentinel) and cur=offs
__global__ void small_scan_k(const int* __restrict__ cnt, int* __restrict__ offs,
                             int* __restrict__ cur, int n){
  __shared__ int s[512];
  int t = threadIdx.x;
  s[t] = (t < n) ? cnt[t] : 0;
  __syncthreads();
  for (int o = 1; o < 512; o <<= 1){
    int v = (t >= o) ? s[t - o] : 0;
    __syncthreads();
    s[t] += v;
    __syncthreads();
  }
  int excl = (t > 0) ? s[t - 1] : 0;
  if (t < n){ offs[t] = excl; cur[t] = excl; }
  if (t == 0) offs[n] = s[n - 1] + ((0 < n) ? 0 : 0), offs[n] = s[n - 1] + cnt[n - 1] - cnt[n - 1], offs[n] = s[n - 1];
}

__global__ void binfill_k(const int* __restrict__ u_idx, const int* __restrict__ i_idx,
                          int* __restrict__ bcur_u, int* __restrict__ bcur_i,
                          int2* __restrict__ bin_u, int2* __restrict__ bin_i){
  __shared__ int hU[NBU_U];
  __shared__ int hI[NBU_I];
  __shared__ int baU[NBU_U];
  __shared__ int baI[NBU_I];
  for (int t = threadIdx.x; t < NBU_U; t += 256) hU[t] = 0;
  for (int t = threadIdx.x; t < NBU_I; t += 256) hI[t] = 0;
  __syncthreads();
  int base = blockIdx.x * CHUNK;
  int end = min(base + CHUNK, NE);
  for (int e = base + threadIdx.x; e < end; e += 256){
    atomicAdd(&hU[u_idx[e] >> BSH], 1);
    atomicAdd(&hI[i_idx[e] >> BSH], 1);
  }
  __syncthreads();
  for (int t = threadIdx.x; t < NBU_U; t += 256){
    int c = hU[t];
    baU[t] = c ? atomicAdd(&bcur_u[t], c) : 0;
    hU[t] = 0;
  }
  for (int t = threadIdx.x; t < NBU_I; t += 256){
    int c = hI[t];
    baI[t] = c ? atomicAdd(&bcur_i[t], c) : 0;
    hI[t] = 0;
  }
  __syncthreads();
  for (int e = base + threadIdx.x; e < end; e += 256){
    int u = u_idx[e], it = i_idx[e];
    int bu = u >> BSH, bi = it >> BSH;
    int pu = baU[bu] + atomicAdd(&hU[bu], 1);
    bin_u[pu] = make_int2(u, it);
    int pi = baI[bi] + atomicAdd(&hI[bi], 1);
    bin_i[pi] = make_int2(it, u);
  }
}

// ---------------- phase 2: per-bucket row counts + fill ----------------

__global__ void bucket_rowcnt_k(const int2* __restrict__ bin, const int* __restrict__ boffs,
                                int* __restrict__ cnt, int nrows){
  __shared__ int h[256];
  h[threadIdx.x] = 0;
  __syncthreads();
  int b = blockIdx.x, r0 = b << BSH;
  int beg = boffs[b], end = boffs[b + 1];
  for (int e = beg + threadIdx.x; e < end; e += 256)
    atomicAdd(&h[bin[e].x - r0], 1);
  __syncthreads();
  int row = r0 + threadIdx.x;
  if (row < nrows) cnt[row] = h[threadIdx.x];
}

__global__ void bucket_fill_k(const int2* __restrict__ bin, const int* __restrict__ boffs,
                              const int* __restrict__ offs, int* __restrict__ adj, int nrows){
  __shared__ int cur[256];
  int b = blockIdx.x, r0 = b << BSH;
  int row = r0 + threadIdx.x;
  cur[threadIdx.x] = (row < nrows) ? offs[row] : 0;
  __syncthreads();
  int beg = boffs[b], end = boffs[b + 1];
  for (int e = beg + threadIdx.x; e < end; e += 256){
    int2 p = bin[e];
    int slot = atomicAdd(&cur[p.x - r0], 1);
    adj[slot] = p.y;
  }
}

// ---------------- row-offset scan (100K / 50K elements) ----------------

__global__ void scan1_k(const int* __restrict__ in, int* __restrict__ out,
                        int* __restrict__ partials, int n){
  __shared__ int sdata[256];
  int tid = threadIdx.x;
  int base = blockIdx.x * 2048 + tid * 8;
  int v[8]; int s = 0;
#pragma unroll
  for (int k = 0; k < 8; ++k){ int i = base + k; int x = (i < n) ? in[i] : 0; v[k] = s; s += x; }
  sdata[tid] = s; __syncthreads();
  for (int off = 1; off < 256; off <<= 1){
    int t = (tid >= off) ? sdata[tid - off] : 0;
    __syncthreads();
    sdata[tid] += t;
    __syncthreads();
  }
  int toff = (tid > 0) ? sdata[tid - 1] : 0;
  if (tid == 255) partials[blockIdx.x] = sdata[255];
#pragma unroll
  for (int k = 0; k < 8; ++k){ int i = base + k; if (i < n) out[i] = v[k] + toff; }
}

__global__ void scan2_k(int* partials, int nb){
  if (blockIdx.x == 0 && threadIdx.x == 0){
    int s = 0;
    for (int i = 0; i < nb; ++i){ int x = partials[i]; partials[i] = s; s += x; }
  }
}

__global__ void scan3_k(int* __restrict__ out, const int* __restrict__ partials,
                        int n, int total){
  int tid = threadIdx.x;
  int base = blockIdx.x * 2048 + tid * 8;
  int add = partials[blockIdx.x];
#pragma unroll
  for (int k = 0; k < 8; ++k){
    int i = base + k;
    if (i < n) out[i] += add;
  }
  if (blockIdx.x == 0 && tid == 0) out[n] = total;
}

// ---------------- misc ----------------

__global__ void norms_k(const int* __restrict__ cnt, float* __restrict__ inv,
                        float* __restrict__ invs, int n){
  int r = blockIdx.x * blockDim.x + threadIdx.x;
  if (r < n){
    int c = cnt[r];
    float d = (c > 0) ? (float)c : 1.0f;
    inv[r]  = 1.0f / d;
    invs[r] = 1.0f / sqrtf(d);
  }
}

__global__ void init_out_k(const float* __restrict__ ue, const float* __restrict__ ie,
                           float* __restrict__ out){
  int idx = blockIdx.x * blockDim.x + threadIdx.x;
  const int un = U_NUM * EMB;
  const int tot = un + I_NUM * EMB;
  if (idx < un) out[idx] = ue[idx];
  else if (idx < tot) out[idx] = ie[idx - un];
}

__global__ void scale_k(float* __restrict__ out, int n, float s){
  int i = blockIdx.x * blockDim.x + threadIdx.x;
  if (i < n) out[i] *= s;
}

// ---------------- gather SpMM ----------------
// out[r] = post[r] * sum_{n in N(r)} (HAS_PRE ? pre[n] : 1) * src[n]
// 16 lanes per row, float4 per lane (256B/row, coalesced). Unroll x4 for ILP.

#define ACC4(vv, ww) { acc.x += (ww)*(vv).x; acc.y += (ww)*(vv).y; \
                       acc.z += (ww)*(vv).z; acc.w += (ww)*(vv).w; }

template<bool HAS_PRE, bool HAS_SUM>
__global__ void spmm_k(const int* __restrict__ offs, const int* __restrict__ adj,
                       const float* __restrict__ src, const float* __restrict__ pre,
                       const float* __restrict__ post, float* __restrict__ dst,
                       float* __restrict__ sum, int nrows){
  int t = blockIdx.x * blockDim.x + threadIdx.x;
  int row = t >> 4;
  if (row >= nrows) return;
  int lane = t & 15;
  int beg = offs[row], end = offs[row + 1];
  float4 acc = make_float4(0.f, 0.f, 0.f, 0.f);
  int j = beg;
  for (; j + 3 < end; j += 4){
    int n0 = adj[j], n1 = adj[j+1], n2 = adj[j+2], n3 = adj[j+3];
    float4 v0 = ((const float4*)(src + (size_t)n0 * EMB))[lane];
    float4 v1 = ((const float4*)(src + (size_t)n1 * EMB))[lane];
    float4 v2 = ((const float4*)(src + (size_t)n2 * EMB))[lane];
    float4 v3 = ((const float4*)(src + (size_t)n3 * EMB))[lane];
    float w0 = HAS_PRE ? pre[n0] : 1.0f;
    float w1 = HAS_PRE ? pre[n1] : 1.0f;
    float w2 = HAS_PRE ? pre[n2] : 1.0f;
    float w3 = HAS_PRE ? pre[n3] : 1.0f;
    ACC4(v0, w0); ACC4(v1, w1); ACC4(v2, w2); ACC4(v3, w3);
  }
  for (; j < end; ++j){
    int n0 = adj[j];
    float4 v0 = ((const float4*)(src + (size_t)n0 * EMB))[lane];
    float w0 = HAS_PRE ? pre[n0] : 1.0f;
    ACC4(v0, w0);
  }
  float p = post[row];
  acc.x *= p; acc.y *= p; acc.z *= p; acc.w *= p;
  ((float4*)(dst + (size_t)row * EMB))[lane] = acc;
  if (HAS_SUM){
    float4* sp = ((float4*)(sum + (size_t)row * EMB)) + lane;
    float4 s = *sp;
    s.x += acc.x; s.y += acc.y; s.z += acc.z; s.w += acc.w;
    *sp = s;
  }
}

// ---------------- driver ----------------

extern "C" void kernel_launch(void* const* d_in, const int* in_sizes, int n_in,
                              void* d_out, int out_size, void* d_ws, size_t ws_size,
                              hipStream_t stream){
  const float* user_emb = (const float*)d_in[0];
  const float* item_emb = (const float*)d_in[1];
  const int*   u_idx    = (const int*)d_in[2];
  const int*   i_idx    = (const int*)d_in[3];
  float* out = (float*)d_out;

  char* w = (char*)d_ws;
  size_t off = 0;
  auto alloc = [&](size_t bytes) -> void* {
    void* p = (void*)(w + off);
    off += (bytes + 255) & ~(size_t)255;
    return p;
  };
  int* cnt_u   = (int*)alloc((size_t)U_NUM * 4);
  int* cnt_i   = (int*)alloc((size_t)I_NUM * 4);
  int* offs_u  = (int*)alloc((size_t)(U_NUM + 1) * 4);
  int* offs_i  = (int*)alloc((size_t)(I_NUM + 1) * 4);
  int* part_u  = (int*)alloc(64 * 4);
  int* part_i  = (int*)alloc(64 * 4);
  int* bcnt_u  = (int*)alloc((size_t)NBU_U * 4);
  int* bcnt_i  = (int*)alloc((size_t)NBU_I * 4);
  int* boffs_u = (int*)alloc((size_t)(NBU_U + 1) * 4);
  int* boffs_i = (int*)alloc((size_t)(NBU_I + 1) * 4);
  int* bcur_u  = (int*)alloc((size_t)NBU_U * 4);
  int* bcur_i  = (int*)alloc((size_t)NBU_I * 4);
  int* adj_u   = (int*)alloc((size_t)NE * 4);
  int* adj_i   = (int*)alloc((size_t)NE * 4);
  float* du_inv  = (float*)alloc((size_t)U_NUM * 4);
  float* du_invs = (float*)alloc((size_t)U_NUM * 4);
  float* di_inv  = (float*)alloc((size_t)I_NUM * 4);
  float* di_invs = (float*)alloc((size_t)I_NUM * 4);
  // embedding temp region — also aliased by the binned-pair arrays, which are
  // dead before the first spmm writes any of these buffers.
  float* emb_region = (float*)alloc((size_t)(U_NUM + I_NUM) * 2 * EMB * 4);
  float* user_e = emb_region;
  float* item_e = user_e + (size_t)U_NUM * EMB;
  float* tmp_i  = item_e + (size_t)I_NUM * EMB;
  float* tmp_u  = tmp_i  + (size_t)I_NUM * EMB;
  int2* bin_u = (int2*)emb_region;               // 16 MB
  int2* bin_i = (int2*)(emb_region + (size_t)NE * 2);  // next 16 MB

  // ---- CSR build (binned) ----
  hipMemsetAsync(bcnt_u, 0, (size_t)NBU_U * 4, stream);
  hipMemsetAsync(bcnt_i, 0, (size_t)NBU_I * 4, stream);

  bucket_hist_k<<<NBLK_E, 256, 0, stream>>>(u_idx, i_idx, bcnt_u, bcnt_i);
  small_scan_k<<<1, 512, 0, stream>>>(bcnt_u, boffs_u, bcur_u, NBU_U);
  small_scan_k<<<1, 512, 0, stream>>>(bcnt_i, boffs_i, bcur_i, NBU_I);
  binfill_k<<<NBLK_E, 256, 0, stream>>>(u_idx, i_idx, bcur_u, bcur_i, bin_u, bin_i);

  bucket_rowcnt_k<<<NBU_U, 256, 0, stream>>>(bin_u, boffs_u, cnt_u, U_NUM);
  bucket_rowcnt_k<<<NBU_I, 256, 0, stream>>>(bin_i, boffs_i, cnt_i, I_NUM);

  int nbu = ceil_div(U_NUM, 2048), nbi = ceil_div(I_NUM, 2048);
  scan1_k<<<nbu, 256, 0, stream>>>(cnt_u, offs_u, part_u, U_NUM);
  scan1_k<<<nbi, 256, 0, stream>>>(cnt_i, offs_i, part_i, I_NUM);
  scan2_k<<<1, 64, 0, stream>>>(part_u, nbu);
  scan2_k<<<1, 64, 0, stream>>>(part_i, nbi);
  scan3_k<<<nbu, 256, 0, stream>>>(offs_u, part_u, U_NUM, NE);
  scan3_k<<<nbi, 256, 0, stream>>>(offs_i, part_i, I_NUM, NE);

  norms_k<<<ceil_div(U_NUM, 256), 256, 0, stream>>>(cnt_u, du_inv, du_invs, U_NUM);
  norms_k<<<ceil_div(I_NUM, 256), 256, 0, stream>>>(cnt_i, di_inv, di_invs, I_NUM);

  bucket_fill_k<<<NBU_U, 256, 0, stream>>>(bin_u, boffs_u, offs_u, adj_u, U_NUM);
  bucket_fill_k<<<NBU_I, 256, 0, stream>>>(bin_i, boffs_i, offs_i, adj_i, I_NUM);

  // ---- propagation ----
  init_out_k<<<ceil_div((U_NUM + I_NUM) * EMB, 256), 256, 0, stream>>>(user_emb, item_emb, out);

  float* sum_u = out;
  float* sum_i = out + (size_t)U_NUM * EMB;
  const float* ue_src = user_emb;
  const float* ie_src = item_emb;
  for (int l = 0; l < NLAYERS; ++l){
    // A: tmp_i = d_i_inv * R^T (d_u_inv_sqrt * user_e)
    spmm_k<true, false><<<ceil_div(I_NUM * 16, 256), 256, 0, stream>>>(
        offs_i, adj_i, ue_src, du_invs, di_inv, tmp_i, nullptr, I_NUM);
    // B: user_e = d_u_inv_sqrt * R tmp_i ; sum_u += user_e
    spmm_k<false, true><<<ceil_div(U_NUM * 16, 256), 256, 0, stream>>>(
        offs_u, adj_u, tmp_i, nullptr, du_invs, user_e, sum_u, U_NUM);
    // C: tmp_u = d_u_inv * R (d_i_inv_sqrt * item_e)
    spmm_k<true, false><<<ceil_div(U_NUM * 16, 256), 256, 0, stream>>>(
        offs_u, adj_u, ie_src, di_invs, du_inv, tmp_u, nullptr, U_NUM);
    // D: item_e = d_i_inv_sqrt * R^T tmp_u ; sum_i += item_e
    spmm_k<false, true><<<ceil_div(I_NUM * 16, 256), 256, 0, stream>>>(
        offs_i, adj_i, tmp_u, nullptr, di_invs, item_e, sum_i, I_NUM);
    ue_src = user_e; ie_src = item_e;
  }

  scale_k<<<ceil_div((U_NUM + I_NUM) * EMB, 256), 256, 0, stream>>>(
      out, (U_NUM + I_NUM) * EMB, 1.0f / (NLAYERS + 1));
}

// Round 3
// 780.493 us; speedup vs baseline: 1.9078x; 1.3889x over previous
//
#include <hip/hip_runtime.h>
#include <hip/hip_fp16.h>
#include <math.h>

#define U_NUM 100000
#define I_NUM 50000
#define NE    2000000
#define EMB   64
#define NLAYERS 3

// bucketing: 256 rows per bucket
#define BSH   8
#define NBU_U ((U_NUM + 255) >> 8)   // 391
#define NBU_I ((I_NUM + 255) >> 8)   // 196
#define CHUNK 8192
#define NBLK_E ((NE + CHUNK - 1) / CHUNK)
#define DBINS 512

static inline int ceil_div(int a, int b){ return (a + b - 1) / b; }

// ---------------- phase 1: bucket partition ----------------

__global__ void bucket_hist_k(const int* __restrict__ u_idx, const int* __restrict__ i_idx,
                              int* __restrict__ bcnt_u, int* __restrict__ bcnt_i){
  __shared__ int hU[NBU_U];
  __shared__ int hI[NBU_I];
  for (int t = threadIdx.x; t < NBU_U; t += 256) hU[t] = 0;
  for (int t = threadIdx.x; t < NBU_I; t += 256) hI[t] = 0;
  __syncthreads();
  int base = blockIdx.x * CHUNK;
  int end = min(base + CHUNK, NE);
  for (int e = base + threadIdx.x; e < end; e += 256){
    atomicAdd(&hU[u_idx[e] >> BSH], 1);
    atomicAdd(&hI[i_idx[e] >> BSH], 1);
  }
  __syncthreads();
  for (int t = threadIdx.x; t < NBU_U; t += 256) if (hU[t]) atomicAdd(&bcnt_u[t], hU[t]);
  for (int t = threadIdx.x; t < NBU_I; t += 256) if (hI[t]) atomicAdd(&bcnt_i[t], hI[t]);
}

// single-block exclusive scan, n <= 512; writes offs[0..n] and cur=offs
__global__ void small_scan_k(const int* __restrict__ cnt, int* __restrict__ offs,
                             int* __restrict__ cur, int n){
  __shared__ int s[512];
  int t = threadIdx.x;
  int v = (t < n) ? cnt[t] : 0;
  s[t] = v; __syncthreads();
  for (int o = 1; o < 512; o <<= 1){
    int x = (t >= o) ? s[t - o] : 0;
    __syncthreads();
    s[t] += x;
    __syncthreads();
  }
  int excl = (t > 0) ? s[t - 1] : 0;
  if (t < n){ offs[t] = excl; cur[t] = excl; }
  if (t == n - 1) offs[n] = s[t];
}

// packed bin entry: (row_local << 24) | neighbor   (neighbor < 2^17)
__global__ void binfill_k(const int* __restrict__ u_idx, const int* __restrict__ i_idx,
                          int* __restrict__ bcur_u, int* __restrict__ bcur_i,
                          int* __restrict__ bin_u, int* __restrict__ bin_i){
  __shared__ int hU[NBU_U];
  __shared__ int hI[NBU_I];
  __shared__ int baU[NBU_U];
  __shared__ int baI[NBU_I];
  for (int t = threadIdx.x; t < NBU_U; t += 256) hU[t] = 0;
  for (int t = threadIdx.x; t < NBU_I; t += 256) hI[t] = 0;
  __syncthreads();
  int base = blockIdx.x * CHUNK;
  int end = min(base + CHUNK, NE);
  for (int e = base + threadIdx.x; e < end; e += 256){
    atomicAdd(&hU[u_idx[e] >> BSH], 1);
    atomicAdd(&hI[i_idx[e] >> BSH], 1);
  }
  __syncthreads();
  for (int t = threadIdx.x; t < NBU_U; t += 256){
    int c = hU[t];
    baU[t] = c ? atomicAdd(&bcur_u[t], c) : 0;
    hU[t] = 0;
  }
  for (int t = threadIdx.x; t < NBU_I; t += 256){
    int c = hI[t];
    baI[t] = c ? atomicAdd(&bcur_i[t], c) : 0;
    hI[t] = 0;
  }
  __syncthreads();
  for (int e = base + threadIdx.x; e < end; e += 256){
    int u = u_idx[e], it = i_idx[e];
    int bu = u >> BSH, bi = it >> BSH;
    int pu = baU[bu] + atomicAdd(&hU[bu], 1);
    bin_u[pu] = ((u & 255) << 24) | it;
    int pi = baI[bi] + atomicAdd(&hI[bi], 1);
    bin_i[pi] = ((it & 255) << 24) | u;
  }
}

// ---------------- phase 2: per-bucket row counts + fill ----------------

__global__ void bucket_rowcnt_k(const int* __restrict__ bin, const int* __restrict__ boffs,
                                int* __restrict__ cnt, int nrows){
  __shared__ int h[256];
  h[threadIdx.x] = 0;
  __syncthreads();
  int b = blockIdx.x, r0 = b << BSH;
  int beg = boffs[b], end = boffs[b + 1];
  for (int e = beg + threadIdx.x; e < end; e += 256)
    atomicAdd(&h[((unsigned)bin[e]) >> 24], 1);
  __syncthreads();
  int row = r0 + threadIdx.x;
  if (row < nrows) cnt[row] = h[threadIdx.x];
}

__global__ void bucket_fill_k(const int* __restrict__ bin, const int* __restrict__ boffs,
                              const int* __restrict__ offs, int* __restrict__ adj, int nrows){
  __shared__ int cur[256];
  int b = blockIdx.x, r0 = b << BSH;
  int row = r0 + threadIdx.x;
  cur[threadIdx.x] = (row < nrows) ? offs[row] : 0;
  __syncthreads();
  int beg = boffs[b], end = boffs[b + 1];
  for (int e = beg + threadIdx.x; e < end; e += 256){
    int v = bin[e];
    int slot = atomicAdd(&cur[((unsigned)v) >> 24], 1);
    adj[slot] = v & 0xFFFFFF;
  }
}

// ---------------- row-offset scan (100K / 50K elements) ----------------

__global__ void scan1_k(const int* __restrict__ in, int* __restrict__ out,
                        int* __restrict__ partials, int n){
  __shared__ int sdata[256];
  int tid = threadIdx.x;
  int base = blockIdx.x * 2048 + tid * 8;
  int v[8]; int s = 0;
#pragma unroll
  for (int k = 0; k < 8; ++k){ int i = base + k; int x = (i < n) ? in[i] : 0; v[k] = s; s += x; }
  sdata[tid] = s; __syncthreads();
  for (int off = 1; off < 256; off <<= 1){
    int t = (tid >= off) ? sdata[tid - off] : 0;
    __syncthreads();
    sdata[tid] += t;
    __syncthreads();
  }
  int toff = (tid > 0) ? sdata[tid - 1] : 0;
  if (tid == 255) partials[blockIdx.x] = sdata[255];
#pragma unroll
  for (int k = 0; k < 8; ++k){ int i = base + k; if (i < n) out[i] = v[k] + toff; }
}

__global__ void scan2_k(int* partials, int nb){
  if (blockIdx.x == 0 && threadIdx.x == 0){
    int s = 0;
    for (int i = 0; i < nb; ++i){ int x = partials[i]; partials[i] = s; s += x; }
  }
}

__global__ void scan3_k(int* __restrict__ out, const int* __restrict__ partials,
                        int n, int total){
  int tid = threadIdx.x;
  int base = blockIdx.x * 2048 + tid * 8;
  int add = partials[blockIdx.x];
#pragma unroll
  for (int k = 0; k < 8; ++k){
    int i = base + k;
    if (i < n) out[i] += add;
  }
  if (blockIdx.x == 0 && tid == 0) out[n] = total;
}

// ---------------- degree sort (counting sort into perm) ----------------

__global__ void deg_hist_k(const int* __restrict__ cnt, int* __restrict__ dhist, int n){
  __shared__ int h[DBINS];
  for (int t = threadIdx.x; t < DBINS; t += 256) h[t] = 0;
  __syncthreads();
  int base = blockIdx.x * 2048;
  int end = min(base + 2048, n);
  for (int r = base + threadIdx.x; r < end; r += 256)
    atomicAdd(&h[min(cnt[r], DBINS - 1)], 1);
  __syncthreads();
  for (int t = threadIdx.x; t < DBINS; t += 256) if (h[t]) atomicAdd(&dhist[t], h[t]);
}

__global__ void deg_scatter_k(const int* __restrict__ cnt, int* __restrict__ dcur,
                              int* __restrict__ perm, int n){
  __shared__ int h[DBINS];
  __shared__ int base_s[DBINS];
  for (int t = threadIdx.x; t < DBINS; t += 256) h[t] = 0;
  __syncthreads();
  int base = blockIdx.x * 2048;
  int end = min(base + 2048, n);
  for (int r = base + threadIdx.x; r < end; r += 256)
    atomicAdd(&h[min(cnt[r], DBINS - 1)], 1);
  __syncthreads();
  for (int t = threadIdx.x; t < DBINS; t += 256){
    int c = h[t];
    base_s[t] = c ? atomicAdd(&dcur[t], c) : 0;
    h[t] = 0;
  }
  __syncthreads();
  for (int r = base + threadIdx.x; r < end; r += 256){
    int b = min(cnt[r], DBINS - 1);
    int pos = base_s[b] + atomicAdd(&h[b], 1);
    perm[pos] = r;
  }
}

// ---------------- misc ----------------

__global__ void norms_k(const int* __restrict__ cnt, float* __restrict__ inv,
                        float* __restrict__ invs, int n){
  int r = blockIdx.x * blockDim.x + threadIdx.x;
  if (r < n){
    int c = cnt[r];
    float d = (c > 0) ? (float)c : 1.0f;
    inv[r]  = 1.0f / d;
    invs[r] = 1.0f / sqrtf(d);
  }
}

__global__ void init_out_k(const float* __restrict__ ue, const float* __restrict__ ie,
                           float* __restrict__ out){
  int idx = blockIdx.x * blockDim.x + threadIdx.x;
  const int un = U_NUM * EMB;
  const int tot = un + I_NUM * EMB;
  if (idx < un) out[idx] = ue[idx];
  else if (idx < tot) out[idx] = ie[idx - un];
}

// out_h[idx] = half(e[idx] * scale[row]); 2 elems per thread
__global__ void conv_h_k(const float* __restrict__ e, const float* __restrict__ scale,
                         __half* __restrict__ out, int n){
  int idx = (blockIdx.x * blockDim.x + threadIdx.x) * 2;
  if (idx < n){
    float s = scale[idx >> 6];
    float2 f = *(const float2*)(e + idx);
    *(__half2*)(out + idx) = __floats2half2_rn(f.x * s, f.y * s);
  }
}

__global__ void scale_k(float* __restrict__ out, int n, float s){
  int i = blockIdx.x * blockDim.x + threadIdx.x;
  if (i < n) out[i] *= s;
}

// ---------------- fp16 gather SpMM ----------------
// 8 lanes per row, each lane owns 8 halves (16B load per edge, 128B/row).
// All pre-scales are folded into src. Epilogue:
//   dst_h[row] = half(acc * post_h[row])          (next spmm's pre-scaled source)
//   if HAS_SUM: sum[row] += acc * post_sum[row]   (fp32 layer accumulation)

template<bool HAS_SUM>
__global__ void spmm_h(const int* __restrict__ offs, const int* __restrict__ adj,
                       const int* __restrict__ perm,
                       const __half* __restrict__ src,
                       const float* __restrict__ post_sum,
                       const float* __restrict__ post_h,
                       __half* __restrict__ dst_h,
                       float* __restrict__ sum, int nrows){
  int t = blockIdx.x * blockDim.x + threadIdx.x;
  int rid = t >> 3;
  if (rid >= nrows) return;
  int lane = t & 7;
  int row = perm[rid];
  int beg = offs[row], end = offs[row + 1];
  const size_t loff = (size_t)(lane << 3);
  float acc[8] = {0.f, 0.f, 0.f, 0.f, 0.f, 0.f, 0.f, 0.f};
  int j = beg;
  for (; j + 1 < end; j += 2){
    int n0 = adj[j], n1 = adj[j + 1];
    float4 r0 = *(const float4*)(src + (((size_t)n0) << 6) + loff);
    float4 r1 = *(const float4*)(src + (((size_t)n1) << 6) + loff);
    union { float4 f; __half2 h[4]; } u0, u1;
    u0.f = r0; u1.f = r1;
#pragma unroll
    for (int k = 0; k < 4; ++k){
      float2 f0 = __half22float2(u0.h[k]);
      float2 f1 = __half22float2(u1.h[k]);
      acc[2*k]     += f0.x + f1.x;
      acc[2*k + 1] += f0.y + f1.y;
    }
  }
  if (j < end){
    int n0 = adj[j];
    float4 r0 = *(const float4*)(src + (((size_t)n0) << 6) + loff);
    union { float4 f; __half2 h[4]; } u0;
    u0.f = r0;
#pragma unroll
    for (int k = 0; k < 4; ++k){
      float2 f0 = __half22float2(u0.h[k]);
      acc[2*k]     += f0.x;
      acc[2*k + 1] += f0.y;
    }
  }
  float ph = post_h[row];
  __half2 o[4];
#pragma unroll
  for (int k = 0; k < 4; ++k)
    o[k] = __floats2half2_rn(acc[2*k] * ph, acc[2*k + 1] * ph);
  *(float4*)(dst_h + (((size_t)row) << 6) + loff) = *(float4*)o;
  if (HAS_SUM){
    float ps = post_sum[row];
    float4* sp = (float4*)(sum + (((size_t)row) << 6) + (loff));
    float4 s0 = sp[0], s1 = sp[1];
    s0.x += acc[0]*ps; s0.y += acc[1]*ps; s0.z += acc[2]*ps; s0.w += acc[3]*ps;
    s1.x += acc[4]*ps; s1.y += acc[5]*ps; s1.z += acc[6]*ps; s1.w += acc[7]*ps;
    sp[0] = s0; sp[1] = s1;
  }
}

// ---------------- driver ----------------

extern "C" void kernel_launch(void* const* d_in, const int* in_sizes, int n_in,
                              void* d_out, int out_size, void* d_ws, size_t ws_size,
                              hipStream_t stream){
  const float* user_emb = (const float*)d_in[0];
  const float* item_emb = (const float*)d_in[1];
  const int*   u_idx    = (const int*)d_in[2];
  const int*   i_idx    = (const int*)d_in[3];
  float* out = (float*)d_out;

  char* w = (char*)d_ws;
  size_t off = 0;
  auto alloc = [&](size_t bytes) -> void* {
    void* p = (void*)(w + off);
    off += (bytes + 255) & ~(size_t)255;
    return p;
  };
  int* cnt_u   = (int*)alloc((size_t)U_NUM * 4);
  int* cnt_i   = (int*)alloc((size_t)I_NUM * 4);
  int* offs_u  = (int*)alloc((size_t)(U_NUM + 1) * 4);
  int* offs_i  = (int*)alloc((size_t)(I_NUM + 1) * 4);
  int* part_u  = (int*)alloc(64 * 4);
  int* part_i  = (int*)alloc(64 * 4);
  int* bcnt_u  = (int*)alloc((size_t)NBU_U * 4);
  int* bcnt_i  = (int*)alloc((size_t)NBU_I * 4);
  int* boffs_u = (int*)alloc((size_t)(NBU_U + 1) * 4);
  int* boffs_i = (int*)alloc((size_t)(NBU_I + 1) * 4);
  int* bcur_u  = (int*)alloc((size_t)NBU_U * 4);
  int* bcur_i  = (int*)alloc((size_t)NBU_I * 4);
  int* dhist_u = (int*)alloc((size_t)DBINS * 4);
  int* dhist_i = (int*)alloc((size_t)DBINS * 4);
  int* doffs_u = (int*)alloc((size_t)(DBINS + 1) * 4);
  int* doffs_i = (int*)alloc((size_t)(DBINS + 1) * 4);
  int* dcur_u  = (int*)alloc((size_t)DBINS * 4);
  int* dcur_i  = (int*)alloc((size_t)DBINS * 4);
  int* perm_u  = (int*)alloc((size_t)U_NUM * 4);
  int* perm_i  = (int*)alloc((size_t)I_NUM * 4);
  int* adj_u   = (int*)alloc((size_t)NE * 4);
  int* adj_i   = (int*)alloc((size_t)NE * 4);
  float* du_inv  = (float*)alloc((size_t)U_NUM * 4);
  float* du_invs = (float*)alloc((size_t)U_NUM * 4);
  float* di_inv  = (float*)alloc((size_t)I_NUM * 4);
  float* di_invs = (float*)alloc((size_t)I_NUM * 4);
  // half-table region, 38.4 MB; the packed bins (16 MB) alias its start and
  // are dead before conv_h_k writes the half tables.
  __half* hreg = (__half*)alloc((size_t)(U_NUM + I_NUM) * 2 * EMB * 2);
  __half* ue_h    = hreg;                                  // U_NUM*64
  __half* ie_h    = ue_h    + (size_t)U_NUM * EMB;         // I_NUM*64
  __half* tmp_i_h = ie_h    + (size_t)I_NUM * EMB;         // I_NUM*64
  __half* tmp_u_h = tmp_i_h + (size_t)I_NUM * EMB;         // U_NUM*64
  int* bin_u = (int*)hreg;            // NE ints (8 MB)
  int* bin_i = bin_u + NE;            // NE ints (8 MB)

  // ---- CSR build (binned, packed) ----
  hipMemsetAsync(bcnt_u, 0, (size_t)NBU_U * 4, stream);
  hipMemsetAsync(bcnt_i, 0, (size_t)NBU_I * 4, stream);
  hipMemsetAsync(dhist_u, 0, (size_t)DBINS * 4, stream);
  hipMemsetAsync(dhist_i, 0, (size_t)DBINS * 4, stream);

  bucket_hist_k<<<NBLK_E, 256, 0, stream>>>(u_idx, i_idx, bcnt_u, bcnt_i);
  small_scan_k<<<1, 512, 0, stream>>>(bcnt_u, boffs_u, bcur_u, NBU_U);
  small_scan_k<<<1, 512, 0, stream>>>(bcnt_i, boffs_i, bcur_i, NBU_I);
  binfill_k<<<NBLK_E, 256, 0, stream>>>(u_idx, i_idx, bcur_u, bcur_i, bin_u, bin_i);

  bucket_rowcnt_k<<<NBU_U, 256, 0, stream>>>(bin_u, boffs_u, cnt_u, U_NUM);
  bucket_rowcnt_k<<<NBU_I, 256, 0, stream>>>(bin_i, boffs_i, cnt_i, I_NUM);

  int nbu = ceil_div(U_NUM, 2048), nbi = ceil_div(I_NUM, 2048);
  scan1_k<<<nbu, 256, 0, stream>>>(cnt_u, offs_u, part_u, U_NUM);
  scan1_k<<<nbi, 256, 0, stream>>>(cnt_i, offs_i, part_i, I_NUM);
  scan2_k<<<1, 64, 0, stream>>>(part_u, nbu);
  scan2_k<<<1, 64, 0, stream>>>(part_i, nbi);
  scan3_k<<<nbu, 256, 0, stream>>>(offs_u, part_u, U_NUM, NE);
  scan3_k<<<nbi, 256, 0, stream>>>(offs_i, part_i, I_NUM, NE);

  norms_k<<<ceil_div(U_NUM, 256), 256, 0, stream>>>(cnt_u, du_inv, du_invs, U_NUM);
  norms_k<<<ceil_div(I_NUM, 256), 256, 0, stream>>>(cnt_i, di_inv, di_invs, I_NUM);

  bucket_fill_k<<<NBU_U, 256, 0, stream>>>(bin_u, boffs_u, offs_u, adj_u, U_NUM);
  bucket_fill_k<<<NBU_I, 256, 0, stream>>>(bin_i, boffs_i, offs_i, adj_i, I_NUM);

  // ---- degree sort ----
  deg_hist_k<<<nbu, 256, 0, stream>>>(cnt_u, dhist_u, U_NUM);
  deg_hist_k<<<nbi, 256, 0, stream>>>(cnt_i, dhist_i, I_NUM);
  small_scan_k<<<1, 512, 0, stream>>>(dhist_u, doffs_u, dcur_u, DBINS);
  small_scan_k<<<1, 512, 0, stream>>>(dhist_i, doffs_i, dcur_i, DBINS);
  deg_scatter_k<<<nbu, 256, 0, stream>>>(cnt_u, dcur_u, perm_u, U_NUM);
  deg_scatter_k<<<nbi, 256, 0, stream>>>(cnt_i, dcur_i, perm_i, I_NUM);

  // ---- propagation (fp16 tables, fp32 accumulation) ----
  init_out_k<<<ceil_div((U_NUM + I_NUM) * EMB, 256), 256, 0, stream>>>(user_emb, item_emb, out);
  conv_h_k<<<ceil_div(U_NUM * EMB / 2, 256), 256, 0, stream>>>(user_emb, du_invs, ue_h, U_NUM * EMB);
  conv_h_k<<<ceil_div(I_NUM * EMB / 2, 256), 256, 0, stream>>>(item_emb, di_invs, ie_h, I_NUM * EMB);

  float* sum_u = out;
  float* sum_i = out + (size_t)U_NUM * EMB;
  for (int l = 0; l < NLAYERS; ++l){
    // A: tmp_i_h = half(d_i_inv * R^T ue_h)           (ue_h pre-scaled by du_invs)
    spmm_h<false><<<ceil_div(I_NUM * 8, 256), 256, 0, stream>>>(
        offs_i, adj_i, perm_i, ue_h, nullptr, di_inv, tmp_i_h, nullptr, I_NUM);
    // B: sum_u += du_invs * R tmp_i_h ; ue_h = half(du_inv * R tmp_i_h)
    spmm_h<true><<<ceil_div(U_NUM * 8, 256), 256, 0, stream>>>(
        offs_u, adj_u, perm_u, tmp_i_h, du_invs, du_inv, ue_h, sum_u, U_NUM);
    // C: tmp_u_h = half(d_u_inv * R ie_h)             (ie_h pre-scaled by di_invs)
    spmm_h<false><<<ceil_div(U_NUM * 8, 256), 256, 0, stream>>>(
        offs_u, adj_u, perm_u, ie_h, nullptr, du_inv, tmp_u_h, nullptr, U_NUM);
    // D: sum_i += di_invs * R^T tmp_u_h ; ie_h = half(di_inv * R^T tmp_u_h)
    spmm_h<true><<<ceil_div(I_NUM * 8, 256), 256, 0, stream>>>(
        offs_i, adj_i, perm_i, tmp_u_h, di_invs, di_inv, ie_h, sum_i, I_NUM);
  }

  scale_k<<<ceil_div((U_NUM + I_NUM) * EMB, 256), 256, 0, stream>>>(
      out, (U_NUM + I_NUM) * EMB, 1.0f / (NLAYERS + 1));
}